// Round 6
// baseline (736.325 us; speedup 1.0000x reference)
//
#include <hip/hip_runtime.h>
#include <hip/hip_bf16.h>
#include <math.h>

#define D 128
#define NEG 0.2f
#define EPSV 1e-16f

// h is stored head-major in 4 slices: h4[sl*N*32 + n*32 + c], sl=0..3, c=0..31.
// Each slice is 1.28 MB -> L2-resident during its aggregation pass (the whole
// point: the edge gather re-reads ~87 MB/layer; sliced, those re-reads hit the
// 4 MiB per-XCD L2 instead of streaming from Infinity Cache).

// ---------------- CSR build (once per call; graph constant across layers) ----------------
__global__ void count_kernel(const int* __restrict__ edst, int E, int N, int* __restrict__ deg){
  int i = blockIdx.x*blockDim.x + threadIdx.x;
  int tot = E + N;
  if (i >= tot) return;
  int d = (i < E) ? edst[i] : (i - E);
  atomicAdd(&deg[d], 1);
}

__global__ void scan_kernel(const int* __restrict__ deg, int N, int* __restrict__ row_ptr, int* __restrict__ cursor){
  __shared__ int part[1024];
  const int CH = 16;                 // 1024*16 = 16384 >= N
  int t = threadIdx.x;
  int base = t*CH;
  int local[CH]; int s = 0;
  #pragma unroll
  for (int j=0;j<CH;j++){ int idx=base+j; int v = (idx<N)? deg[idx] : 0; local[j]=s; s+=v; }
  part[t]=s; __syncthreads();
  for (int off=1; off<1024; off<<=1){
    int v = (t>=off)? part[t-off] : 0;
    __syncthreads();
    part[t]+=v;
    __syncthreads();
  }
  int cb = (t==0)? 0 : part[t-1];
  #pragma unroll
  for (int j=0;j<CH;j++){ int idx=base+j; if(idx<N){ int r=cb+local[j]; row_ptr[idx]=r; cursor[idx]=r; } }
  if (t==1023) row_ptr[N]=part[1023];
}

__global__ void scatter_kernel(const int* __restrict__ esrc, const int* __restrict__ edst,
                               int E, int N, int* __restrict__ cursor, int* __restrict__ csr_src){
  int i = blockIdx.x*blockDim.x + threadIdx.x;
  int tot = E + N;
  if (i>=tot) return;
  int s, d2;
  if (i<E){ s=esrc[i]; d2=edst[i]; } else { s=i-E; d2=i-E; }
  int pos = atomicAdd(&cursor[d2],1);
  csr_src[pos]=s;
}

// ---------------- GEMV phase (shared): rbuf rows @ W -> h4 + es/ed ----------------
// 512 threads = 4 col-groups of 128; each group computes 2 nodes' 128 outputs.
// Per 4 k-steps: 4 coalesced W loads + 2 ds_read_b128 + 8 FMA per thread.
template<int HNEXT>
__device__ __forceinline__ void gemv_phase(const float (*rbuf)[D], int nbase, int N,
                                           const float* __restrict__ Wn,
                                           const float* __restrict__ av_, const float* __restrict__ bv_,
                                           float* __restrict__ h4_out, float* __restrict__ es_out,
                                           float* __restrict__ ed_out, float* pE, float* pD){
  const int t   = threadIdx.x;
  const int col = t & (D-1);
  const int g   = t >> 7;                 // 0..3
  const float av = av_[col], bv = bv_[col];
  const float* __restrict__ r0 = rbuf[g*2+0];
  const float* __restrict__ r1 = rbuf[g*2+1];
  float a0=0.f, a1=0.f;
  #pragma unroll 4
  for (int k=0;k<D;k+=4){
    const float w0 = Wn[(size_t)(k+0)*D + col];
    const float w1 = Wn[(size_t)(k+1)*D + col];
    const float w2 = Wn[(size_t)(k+2)*D + col];
    const float w3 = Wn[(size_t)(k+3)*D + col];
    const float4 x0 = *reinterpret_cast<const float4*>(r0 + k);
    const float4 x1 = *reinterpret_cast<const float4*>(r1 + k);
    a0 = fmaf(x0.w, w3, fmaf(x0.z, w2, fmaf(x0.y, w1, fmaf(x0.x, w0, a0))));
    a1 = fmaf(x1.w, w3, fmaf(x1.z, w2, fmaf(x1.y, w1, fmaf(x1.x, w0, a1))));
  }
  const int sl = col >> 5, cc = col & 31;
  if constexpr (HNEXT==4){
    #pragma unroll
    for (int j=0;j<2;j++){
      const float acc = j ? a1 : a0;
      const int n = nbase + g*2 + j;
      if (n < N){                          // group-uniform
        h4_out[(size_t)sl*N*32 + (size_t)n*32 + cc] = acc;
        float ps = acc*av, pd = acc*bv;
        #pragma unroll
        for (int off=16; off; off>>=1){ ps += __shfl_xor(ps, off, 32); pd += __shfl_xor(pd, off, 32); }
        if ((col&31)==0){ es_out[n*4 + (col>>5)] = ps; ed_out[n*4 + (col>>5)] = pd; }
      }
    }
  } else {
    const int half = (t>>6)&1;
    #pragma unroll
    for (int j=0;j<2;j++){
      const float acc = j ? a1 : a0;
      const int n = nbase + g*2 + j;
      float ps = 0.f, pd = 0.f;
      if (n < N){
        h4_out[(size_t)sl*N*32 + (size_t)n*32 + cc] = acc;
        ps = acc*av; pd = acc*bv;
      }
      #pragma unroll
      for (int off=32; off; off>>=1){ ps += __shfl_xor(ps, off, 64); pd += __shfl_xor(pd, off, 64); }
      if ((t&63)==0){ pE[(g*2+j)*2+half]=ps; pD[(g*2+j)*2+half]=pd; }
    }
    __syncthreads();
    if (t < 8){
      const int n = nbase + t;
      if (n < N){
        es_out[n] = pE[t*2+0]+pE[t*2+1];
        ed_out[n] = pD[t*2+0]+pD[t*2+1];
      }
    }
  }
}

// ---------------- Layer-0 linear: x rows -> LDS -> GEMV ----------------
__launch_bounds__(512, 4)
__global__ void linear0_kernel(const float* __restrict__ x, const float* __restrict__ Wn,
                               const float* __restrict__ an_src, const float* __restrict__ an_dst,
                               int N, float* __restrict__ h4_out, float* __restrict__ es_out, float* __restrict__ ed_out){
  __shared__ float rbuf[8][D];
  __shared__ float pE[16], pD[16];
  const int t = threadIdx.x;
  const int nbase = blockIdx.x*8;
  {
    const int row = t >> 6;
    const int cc  = (t & 63)*2;
    int n = nbase + row; if (n > N-1) n = N-1;
    const float2 v = *reinterpret_cast<const float2*>(x + (size_t)n*D + cc);
    rbuf[row][cc] = v.x; rbuf[row][cc+1] = v.y;
  }
  __syncthreads();
  gemv_phase<4>(rbuf, nbase, N, Wn, an_src, an_dst, h4_out, es_out, ed_out, pE, pD);
}

// ---------------- Fused: aggregate(layer l, heads=4) + linear(layer l+1) ----------------
// Phase A per 64-edge tile: gather csr+es, exp -> (offset,p) float2 per head in LDS.
// Phase B: 4 slice passes (slice outer => gather window is one 1.28MB slice, L2-hot).
//   half = lane>>5 picks edge e or e+1; c = lane&31 owns channel. z per head via
//   half-partials combined with shfl_xor(32). Single-pass softmax (exp clamped at 80).
template<int HNEXT>
__launch_bounds__(512, 4)
__global__ void fused_kernel(const float* __restrict__ h4, const float* __restrict__ es, const float* __restrict__ ed,
                             const int* __restrict__ row_ptr, const int* __restrict__ csr_src,
                             const float* __restrict__ bias,
                             const float* __restrict__ Wn, const float* __restrict__ an_src, const float* __restrict__ an_dst,
                             int N, float* __restrict__ h4_out, float* __restrict__ es_out, float* __restrict__ ed_out){
  __shared__ float2 sSP[8][4][64];   // 16 KB: (.x = float-bitcast elem offset s*32, .y = p)
  __shared__ float rbuf[8][D];       // 4 KB
  __shared__ float pE[16], pD[16];
  const int t = threadIdx.x;
  const int lane = t & 63;
  const int wid  = t >> 6;
  const int n = blockIdx.x*8 + wid;

  if (n < N){
    const int start = row_ptr[n], end = row_ptr[n+1];
    const float ed0 = ed[n*4+0], ed1 = ed[n*4+1], ed2 = ed[n*4+2], ed3 = ed[n*4+3];
    const int half = lane >> 5;
    const int c    = lane & 31;
    float acc[4] = {0.f,0.f,0.f,0.f};
    float zp[4]  = {0.f,0.f,0.f,0.f};

    for (int t0 = start; t0 < end; t0 += 64){
      const int cnt = min(64, end - t0);
      // --- phase A: edge-parallel p computation (lanes >= cnt write zero padding) ---
      {
        int s = 0; float p0=0.f,p1=0.f,p2=0.f,p3=0.f;
        if (lane < cnt){
          s = csr_src[t0 + lane];
          const float4 e4 = *reinterpret_cast<const float4*>(es + (size_t)s*4);
          float q0 = e4.x + ed0; q0 = (q0>=0.f)? q0 : NEG*q0; q0 = fminf(q0, 80.f);
          float q1 = e4.y + ed1; q1 = (q1>=0.f)? q1 : NEG*q1; q1 = fminf(q1, 80.f);
          float q2 = e4.z + ed2; q2 = (q2>=0.f)? q2 : NEG*q2; q2 = fminf(q2, 80.f);
          float q3 = e4.w + ed3; q3 = (q3>=0.f)? q3 : NEG*q3; q3 = fminf(q3, 80.f);
          p0 = __expf(q0); p1 = __expf(q1); p2 = __expf(q2); p3 = __expf(q3);
        }
        const float so = __int_as_float(s*32);
        sSP[wid][0][lane] = make_float2(so, p0);
        sSP[wid][1][lane] = make_float2(so, p1);
        sSP[wid][2][lane] = make_float2(so, p2);
        sSP[wid][3][lane] = make_float2(so, p3);
      }
      // --- phase B: slice passes; 2 edges per iteration (one per half-wave) ---
      const int cr = (cnt + 1) & ~1;
      #pragma unroll
      for (int sl=0; sl<4; sl++){
        const float* __restrict__ hs = h4 + (size_t)sl*N*32;
        float a = acc[sl], zz = zp[sl];
        #pragma unroll 2
        for (int e = 0; e < cr; e += 2){
          const float2 e0 = sSP[wid][sl][e];
          const float2 e1 = sSP[wid][sl][e+1];
          const int   off = __float_as_int(half ? e1.x : e0.x);
          const float p   = half ? e1.y : e0.y;
          const float hv  = hs[off + c];
          zz += p;
          a = fmaf(p, hv, a);
        }
        acc[sl] = a; zp[sl] = zz;
      }
    }
    // combine half-wave partials, finish softmax, bias+relu -> rbuf
    #pragma unroll
    for (int sl=0; sl<4; sl++){
      const float z = zp[sl] + __shfl_xor(zp[sl], 32, 64);
      const float a = acc[sl] + __shfl_xor(acc[sl], 32, 64);
      const float inv = 1.f/(z + EPSV);
      float o = fmaf(a, inv, bias[sl*32 + c]);
      o = fmaxf(o, 0.f);                     // mid layers always relu
      rbuf[wid][sl*32 + c] = o;              // both halves write same value (benign)
    }
  }
  __syncthreads();
  gemv_phase<HNEXT>(rbuf, blockIdx.x*8, N, Wn, an_src, an_dst, h4_out, es_out, ed_out, pE, pD);
}

// ---------------- Final aggregation (heads=1, no relu) -> d_out ----------------
__launch_bounds__(512, 4)
__global__ void final_agg_kernel(const float* __restrict__ h4, const float* __restrict__ es, const float* __restrict__ ed,
                                 const int* __restrict__ row_ptr, const int* __restrict__ csr_src,
                                 const float* __restrict__ bias, float* __restrict__ out, int N){
  __shared__ float2 sSP[8][64];      // single head: p shared across the 4 channel slices
  const int t = threadIdx.x;
  const int lane = t & 63;
  const int wid  = t >> 6;
  const int n = blockIdx.x*8 + wid;
  if (n >= N) return;
  const int start = row_ptr[n], end = row_ptr[n+1];
  const float edn = ed[n];
  const int half = lane >> 5;
  const int c    = lane & 31;
  float acc[4] = {0.f,0.f,0.f,0.f};
  float zph = 0.f;

  for (int t0 = start; t0 < end; t0 += 64){
    const int cnt = min(64, end - t0);
    {
      int s = 0; float p0 = 0.f;
      if (lane < cnt){
        s = csr_src[t0 + lane];
        float q0 = es[s] + edn; q0 = (q0>=0.f)? q0 : NEG*q0; q0 = fminf(q0, 80.f);
        p0 = __expf(q0);
      }
      sSP[wid][lane] = make_float2(__int_as_float(s*32), p0);
    }
    const int cr = (cnt + 1) & ~1;
    #pragma unroll
    for (int sl=0; sl<4; sl++){
      const float* __restrict__ hs = h4 + (size_t)sl*N*32;
      float a = acc[sl];
      #pragma unroll 2
      for (int e = 0; e < cr; e += 2){
        const float2 e0 = sSP[wid][e];
        const float2 e1 = sSP[wid][e+1];
        const int   off = __float_as_int(half ? e1.x : e0.x);
        const float p   = half ? e1.y : e0.y;
        const float hv  = hs[off + c];
        if (sl == 0) zph += p;
        a = fmaf(p, hv, a);
      }
      acc[sl] = a;
    }
  }
  const float z = zph + __shfl_xor(zph, 32, 64);
  const float inv = 1.f/(z + EPSV);
  #pragma unroll
  for (int sl=0; sl<4; sl++){
    const float a = acc[sl] + __shfl_xor(acc[sl], 32, 64);
    const float o = fmaf(a, inv, bias[sl*32 + c]);
    if (half == 0) out[(size_t)n*D + sl*32 + c] = o;
  }
}

extern "C" void kernel_launch(void* const* d_in, const int* in_sizes, int n_in,
                              void* d_out, int out_size, void* d_ws, size_t ws_size,
                              hipStream_t stream) {
  const float* x          = (const float*)d_in[0];
  const int*   ei         = (const int*)d_in[1];
  const float* Ws         = (const float*)d_in[2];
  const float* a_src      = (const float*)d_in[3];
  const float* a_dst      = (const float*)d_in[4];
  const float* bs         = (const float*)d_in[5];
  const float* W_last     = (const float*)d_in[6];
  const float* a_src_last = (const float*)d_in[7];
  const float* a_dst_last = (const float*)d_in[8];
  const float* b_last     = (const float*)d_in[9];

  const int N = in_sizes[0]/D;
  const int E = in_sizes[1]/2;
  const int L = in_sizes[2]/(D*D);   // 19 mid layers
  const int* esrc = ei;
  const int* edst = ei + E;

  // workspace layout (double-buffered h4/es/ed)
  char* ws = (char*)d_ws;
  float* h0  = (float*)ws;  ws += (size_t)N*D*sizeof(float);
  float* h1  = (float*)ws;  ws += (size_t)N*D*sizeof(float);
  float* es0 = (float*)ws;  ws += (size_t)N*4*sizeof(float);
  float* es1 = (float*)ws;  ws += (size_t)N*4*sizeof(float);
  float* ed0 = (float*)ws;  ws += (size_t)N*4*sizeof(float);
  float* ed1 = (float*)ws;  ws += (size_t)N*4*sizeof(float);
  int* deg     = (int*)ws;  ws += (size_t)N*sizeof(int);
  int* row_ptr = (int*)ws;  ws += (size_t)(N+1)*sizeof(int);
  int* cursor  = (int*)ws;  ws += (size_t)N*sizeof(int);
  int* csr_src = (int*)ws;  ws += (size_t)(E+N)*sizeof(int);

  const int tot = E + N;
  hipMemsetAsync(deg, 0, (size_t)N*sizeof(int), stream);
  count_kernel<<<(tot+255)/256, 256, 0, stream>>>(edst, E, N, deg);
  scan_kernel<<<1, 1024, 0, stream>>>(deg, N, row_ptr, cursor);
  scatter_kernel<<<(tot+255)/256, 256, 0, stream>>>(esrc, edst, E, N, cursor, csr_src);

  const int gA = (N + 7)/8;

  // layer 0 linear
  linear0_kernel<<<gA, 512, 0, stream>>>(x, Ws, a_src, a_dst, N, h0, es0, ed0);

  const float *hc = h0, *esc = es0, *edc = ed0;
  float *hn = h1, *esn = es1, *edn = ed1;

  // fused aggregate(l) + linear(l+1), l = 0..L-2
  for (int l = 0; l < L-1; l++){
    fused_kernel<4><<<gA, 512, 0, stream>>>(hc, esc, edc, row_ptr, csr_src,
                                            bs + (size_t)l*D,
                                            Ws + (size_t)(l+1)*D*D, a_src + (size_t)(l+1)*D, a_dst + (size_t)(l+1)*D,
                                            N, hn, esn, edn);
    const float* tf;
    tf = hc;  hc = hn;  hn = (float*)tf;
    tf = esc; esc = esn; esn = (float*)tf;
    tf = edc; edc = edn; edn = (float*)tf;
  }

  // fused aggregate(L-1) + last linear (heads=1)
  fused_kernel<1><<<gA, 512, 0, stream>>>(hc, esc, edc, row_ptr, csr_src,
                                          bs + (size_t)(L-1)*D,
                                          W_last, a_src_last, a_dst_last,
                                          N, hn, esn, edn);
  {
    const float* tf;
    tf = hc;  hc = hn;  hn = (float*)tf;
    tf = esc; esc = esn; esn = (float*)tf;
    tf = edc; edc = edn; edn = (float*)tf;
  }

  // final aggregation (heads=1, no relu) -> d_out
  final_agg_kernel<<<gA, 512, 0, stream>>>(hc, esc, edc, row_ptr, csr_src, b_last, (float*)d_out, N);
}

// Round 7
// 483.326 us; speedup vs baseline: 1.5235x; 1.5235x over previous
//
#include <hip/hip_runtime.h>
#include <hip/hip_bf16.h>
#include <math.h>

#define D 128
#define NEG 0.2f
#define EPSV 1e-16f
#define NPB 20          // nodes per block (N=10000 -> exactly 500 blocks, ~2/CU)
#define GRP_N 5         // nodes per 128-col group in GEMV (4 groups * 5 = NPB)

// ---------------- CSR build (once per call; graph constant across layers) ----------------
__global__ void count_kernel(const int* __restrict__ edst, int E, int N, int* __restrict__ deg){
  int i = blockIdx.x*blockDim.x + threadIdx.x;
  int tot = E + N;
  if (i >= tot) return;
  int d = (i < E) ? edst[i] : (i - E);
  atomicAdd(&deg[d], 1);
}

__global__ void scan_kernel(const int* __restrict__ deg, int N, int* __restrict__ row_ptr, int* __restrict__ cursor){
  __shared__ int part[1024];
  const int CH = 16;                 // 1024*16 = 16384 >= N
  int t = threadIdx.x;
  int base = t*CH;
  int local[CH]; int s = 0;
  #pragma unroll
  for (int j=0;j<CH;j++){ int idx=base+j; int v = (idx<N)? deg[idx] : 0; local[j]=s; s+=v; }
  part[t]=s; __syncthreads();
  for (int off=1; off<1024; off<<=1){
    int v = (t>=off)? part[t-off] : 0;
    __syncthreads();
    part[t]+=v;
    __syncthreads();
  }
  int cb = (t==0)? 0 : part[t-1];
  #pragma unroll
  for (int j=0;j<CH;j++){ int idx=base+j; if(idx<N){ int r=cb+local[j]; row_ptr[idx]=r; cursor[idx]=r; } }
  if (t==1023) row_ptr[N]=part[1023];
}

__global__ void scatter_kernel(const int* __restrict__ esrc, const int* __restrict__ edst,
                               int E, int N, int* __restrict__ cursor, int* __restrict__ csr_src){
  int i = blockIdx.x*blockDim.x + threadIdx.x;
  int tot = E + N;
  if (i>=tot) return;
  int s, d2;
  if (i<E){ s=esrc[i]; d2=edst[i]; } else { s=i-E; d2=i-E; }
  int pos = atomicAdd(&cursor[d2],1);
  csr_src[pos]=s;
}

// ---------------- GEMV phase: rbuf rows @ W -> h + es/ed ----------------
// 512 threads = 4 col-groups of 128; each group computes GRP_N nodes.
// Per k: 1 coalesced W load feeds GRP_N FMAs per thread (W amortized 20x/block).
template<int HNEXT>
__device__ __forceinline__ void gemv_phase(const float (*rbuf)[D], int nbase, int N,
                                           const float* __restrict__ Wn,
                                           const float* __restrict__ av_, const float* __restrict__ bv_,
                                           float* __restrict__ h_out, float* __restrict__ es_out,
                                           float* __restrict__ ed_out, float (*pE)[2], float (*pD)[2]){
  const int t   = threadIdx.x;
  const int col = t & (D-1);
  const int g   = t >> 7;                 // 0..3
  const float av = av_[col], bv = bv_[col];
  const float* __restrict__ r[GRP_N];
  #pragma unroll
  for (int j=0;j<GRP_N;j++) r[j] = rbuf[g*GRP_N + j];
  float acc[GRP_N];
  #pragma unroll
  for (int j=0;j<GRP_N;j++) acc[j]=0.f;

  #pragma unroll 4
  for (int k=0;k<D;k+=4){
    const float w0 = Wn[(size_t)(k+0)*D + col];
    const float w1 = Wn[(size_t)(k+1)*D + col];
    const float w2 = Wn[(size_t)(k+2)*D + col];
    const float w3 = Wn[(size_t)(k+3)*D + col];
    #pragma unroll
    for (int j=0;j<GRP_N;j++){
      const float4 xv = *reinterpret_cast<const float4*>(r[j] + k);
      acc[j] = fmaf(xv.w, w3, fmaf(xv.z, w2, fmaf(xv.y, w1, fmaf(xv.x, w0, acc[j]))));
    }
  }

  if constexpr (HNEXT==4){
    #pragma unroll
    for (int j=0;j<GRP_N;j++){
      const int n = nbase + g*GRP_N + j;
      if (n < N){                          // group-uniform
        h_out[(size_t)n*D + col] = acc[j];
        float ps = acc[j]*av, pd = acc[j]*bv;
        #pragma unroll
        for (int off=16; off; off>>=1){ ps += __shfl_xor(ps, off, 32); pd += __shfl_xor(pd, off, 32); }
        if ((col&31)==0){ es_out[n*4 + (col>>5)] = ps; ed_out[n*4 + (col>>5)] = pd; }
      }
    }
  } else {
    const int half = (t>>6)&1;
    #pragma unroll
    for (int j=0;j<GRP_N;j++){
      const int n = nbase + g*GRP_N + j;
      float ps = 0.f, pd = 0.f;
      if (n < N){
        h_out[(size_t)n*D + col] = acc[j];
        ps = acc[j]*av; pd = acc[j]*bv;
      }
      #pragma unroll
      for (int off=32; off; off>>=1){ ps += __shfl_xor(ps, off, 64); pd += __shfl_xor(pd, off, 64); }
      if ((t&63)==0){ pE[g*GRP_N+j][half]=ps; pD[g*GRP_N+j][half]=pd; }
    }
    __syncthreads();
    if (t < NPB){
      const int n = nbase + t;
      if (n < N){
        es_out[n] = pE[t][0]+pE[t][1];
        ed_out[n] = pD[t][0]+pD[t][1];
      }
    }
  }
}

// ---------------- Layer-0 linear: x rows -> LDS -> GEMV ----------------
__launch_bounds__(512, 4)
__global__ void linear0_kernel(const float* __restrict__ x, const float* __restrict__ Wn,
                               const float* __restrict__ an_src, const float* __restrict__ an_dst,
                               int N, float* __restrict__ h_out, float* __restrict__ es_out, float* __restrict__ ed_out){
  __shared__ float rbuf[NPB][D];
  __shared__ float pE[NPB][2], pD[NPB][2];
  const int t = threadIdx.x;
  const int nbase = blockIdx.x*NPB;
  for (int i = t; i < NPB*(D/4); i += 512){
    const int row = i >> 5;            // i / 32
    const int cc  = (i & 31) * 4;
    int n = nbase + row; if (n > N-1) n = N-1;
    const float4 v = *reinterpret_cast<const float4*>(x + (size_t)n*D + cc);
    *reinterpret_cast<float4*>(&rbuf[row][cc]) = v;
  }
  __syncthreads();
  gemv_phase<4>(rbuf, nbase, N, Wn, an_src, an_dst, h_out, es_out, ed_out, pE, pD);
}

// ---------------- Fused: aggregate(layer l, heads=4) + linear(layer l+1) ----------------
// Phase 1: 8 waves, each handles nodes local = wid, wid+8, ... (<NPB) sequentially.
//   Per 64-edge tile: phase A lanes gather csr+es, exp -> sIdx (s*D) + packed sP[4] in LDS
//   (zero-padded beyond cnt). Phase B: half-wave edge split -- 32 lanes x float4 = one
//   full h row per instruction, 2 edges/iter, unroll 4 (>=4 rows in flight). Lane owns
//   channels [ (lane&31)*4 , +4 ), head = (lane&31)>>3. Single-pass softmax (exp<=e^80),
//   half partials combined via shfl_xor(32). Result row (bias+relu) -> rbuf.
// Phase 2: GEMV of the NPB aggregated rows with next layer's W + attention dots.
template<int HNEXT>
__launch_bounds__(512, 4)
__global__ void fused_kernel(const float* __restrict__ h, const float* __restrict__ es, const float* __restrict__ ed,
                             const int* __restrict__ row_ptr, const int* __restrict__ csr_src,
                             const float* __restrict__ bias,
                             const float* __restrict__ Wn, const float* __restrict__ an_src, const float* __restrict__ an_dst,
                             int N, float* __restrict__ h_out, float* __restrict__ es_out, float* __restrict__ ed_out){
  __shared__ int   sIdx[8][64];      // 2 KB  (premultiplied: s*D)
  __shared__ float sP[8][64][4];     // 8 KB  (p per head, packed float4 per edge)
  __shared__ float rbuf[NPB][D];     // 10 KB
  __shared__ float pE[NPB][2], pD[NPB][2];
  const int t = threadIdx.x;
  const int lane = t & 63;
  const int wid  = t >> 6;
  const int nbase = blockIdx.x*NPB;
  const int half = lane >> 5;
  const int l32  = lane & 31;
  const int cq   = l32 * 4;          // my 4 channels
  const int myh4 = l32 >> 3;         // my head

  for (int local = wid; local < NPB; local += 8){
    const int n = nbase + local;
    if (n >= N) continue;            // no barriers inside; safe
    const int start = row_ptr[n], end = row_ptr[n+1];
    const float ed0 = ed[n*4+0], ed1 = ed[n*4+1], ed2 = ed[n*4+2], ed3 = ed[n*4+3];
    float4 acc = make_float4(0.f,0.f,0.f,0.f);
    float zph = 0.f;

    for (int t0 = start; t0 < end; t0 += 64){
      const int cnt = min(64, end - t0);
      // --- phase A: edge-parallel p computation (zero-padded beyond cnt) ---
      {
        int sOff = 0; float p0=0.f,p1=0.f,p2=0.f,p3=0.f;
        if (lane < cnt){
          const int s = csr_src[t0 + lane];
          sOff = s*D;
          const float4 e4 = *reinterpret_cast<const float4*>(es + (size_t)s*4);
          float q0 = e4.x + ed0; q0 = (q0>=0.f)? q0 : NEG*q0; q0 = fminf(q0, 80.f);
          float q1 = e4.y + ed1; q1 = (q1>=0.f)? q1 : NEG*q1; q1 = fminf(q1, 80.f);
          float q2 = e4.z + ed2; q2 = (q2>=0.f)? q2 : NEG*q2; q2 = fminf(q2, 80.f);
          float q3 = e4.w + ed3; q3 = (q3>=0.f)? q3 : NEG*q3; q3 = fminf(q3, 80.f);
          p0 = __expf(q0); p1 = __expf(q1); p2 = __expf(q2); p3 = __expf(q3);
        }
        sIdx[wid][lane] = sOff;
        *reinterpret_cast<float4*>(&sP[wid][lane][0]) = make_float4(p0,p1,p2,p3);
      }
      // --- phase B: 2 edges/iter (one per half-wave), full row per instruction ---
      const int cr = (cnt + 1) & ~1;
      #pragma unroll 4
      for (int e = 0; e < cr; e += 2){
        const int   off = sIdx[wid][e + half];
        const float p   = sP[wid][e + half][myh4];
        const float4 hv = *reinterpret_cast<const float4*>(h + (size_t)off + cq);
        zph += p;
        acc.x = fmaf(p, hv.x, acc.x);
        acc.y = fmaf(p, hv.y, acc.y);
        acc.z = fmaf(p, hv.z, acc.z);
        acc.w = fmaf(p, hv.w, acc.w);
      }
    }
    // combine half-wave partials; finish softmax; bias + relu -> rbuf
    const float z = zph + __shfl_xor(zph, 32, 64);
    acc.x += __shfl_xor(acc.x, 32, 64);
    acc.y += __shfl_xor(acc.y, 32, 64);
    acc.z += __shfl_xor(acc.z, 32, 64);
    acc.w += __shfl_xor(acc.w, 32, 64);
    const float inv = 1.f/(z + EPSV);
    const float4 bv = *reinterpret_cast<const float4*>(bias + cq);
    float4 o;
    o.x = fmaxf(fmaf(acc.x, inv, bv.x), 0.f);
    o.y = fmaxf(fmaf(acc.y, inv, bv.y), 0.f);
    o.z = fmaxf(fmaf(acc.z, inv, bv.z), 0.f);
    o.w = fmaxf(fmaf(acc.w, inv, bv.w), 0.f);
    if (half == 0) *reinterpret_cast<float4*>(&rbuf[local][cq]) = o;
  }
  __syncthreads();
  gemv_phase<HNEXT>(rbuf, nbase, N, Wn, an_src, an_dst, h_out, es_out, ed_out, pE, pD);
}

// ---------------- Final aggregation (heads=1, no relu) -> d_out ----------------
__launch_bounds__(512, 8)
__global__ void final_agg_kernel(const float* __restrict__ h, const float* __restrict__ es, const float* __restrict__ ed,
                                 const int* __restrict__ row_ptr, const int* __restrict__ csr_src,
                                 const float* __restrict__ bias, float* __restrict__ out, int N){
  __shared__ int   sIdx[8][64];
  __shared__ float sP[8][64];
  const int lane = threadIdx.x & 63;
  const int wid  = threadIdx.x >> 6;
  const int n = blockIdx.x*8 + wid;
  if (n >= N) return;
  const int start = row_ptr[n], end = row_ptr[n+1];
  const float edn = ed[n];
  const int c0 = lane*2;
  float accx=0.f, accy=0.f, z=0.f;
  for (int t0 = start; t0 < end; t0 += 64){
    const int cnt = min(64, end - t0);
    if (lane < cnt){
      const int s = csr_src[t0 + lane];
      sIdx[wid][lane] = s;
      float p0 = es[s] + edn; p0 = (p0>=0.f)? p0 : NEG*p0; p0 = fminf(p0, 80.f);
      sP[wid][lane] = __expf(p0);
    }
    #pragma unroll 8
    for (int e = 0; e < cnt; e++){
      const int s = sIdx[wid][e];
      const float p = sP[wid][e];
      const float2 hv = *reinterpret_cast<const float2*>(h + (size_t)s*D + c0);
      z += p;
      accx = fmaf(p, hv.x, accx);
      accy = fmaf(p, hv.y, accy);
    }
  }
  const float inv = 1.f/(z + EPSV);
  const float ox = fmaf(accx, inv, bias[c0]), oy = fmaf(accy, inv, bias[c0+1]);
  *reinterpret_cast<float2*>(out + (size_t)n*D + c0) = make_float2(ox, oy);
}

extern "C" void kernel_launch(void* const* d_in, const int* in_sizes, int n_in,
                              void* d_out, int out_size, void* d_ws, size_t ws_size,
                              hipStream_t stream) {
  const float* x          = (const float*)d_in[0];
  const int*   ei         = (const int*)d_in[1];
  const float* Ws         = (const float*)d_in[2];
  const float* a_src      = (const float*)d_in[3];
  const float* a_dst      = (const float*)d_in[4];
  const float* bs         = (const float*)d_in[5];
  const float* W_last     = (const float*)d_in[6];
  const float* a_src_last = (const float*)d_in[7];
  const float* a_dst_last = (const float*)d_in[8];
  const float* b_last     = (const float*)d_in[9];

  const int N = in_sizes[0]/D;
  const int E = in_sizes[1]/2;
  const int L = in_sizes[2]/(D*D);   // 19 mid layers
  const int* esrc = ei;
  const int* edst = ei + E;

  // workspace layout (double-buffered h/es/ed)
  char* ws = (char*)d_ws;
  float* h0  = (float*)ws;  ws += (size_t)N*D*sizeof(float);
  float* h1  = (float*)ws;  ws += (size_t)N*D*sizeof(float);
  float* es0 = (float*)ws;  ws += (size_t)N*4*sizeof(float);
  float* es1 = (float*)ws;  ws += (size_t)N*4*sizeof(float);
  float* ed0 = (float*)ws;  ws += (size_t)N*4*sizeof(float);
  float* ed1 = (float*)ws;  ws += (size_t)N*4*sizeof(float);
  int* deg     = (int*)ws;  ws += (size_t)N*sizeof(int);
  int* row_ptr = (int*)ws;  ws += (size_t)(N+1)*sizeof(int);
  int* cursor  = (int*)ws;  ws += (size_t)N*sizeof(int);
  int* csr_src = (int*)ws;  ws += (size_t)(E+N)*sizeof(int);

  const int tot = E + N;
  hipMemsetAsync(deg, 0, (size_t)N*sizeof(int), stream);
  count_kernel<<<(tot+255)/256, 256, 0, stream>>>(edst, E, N, deg);
  scan_kernel<<<1, 1024, 0, stream>>>(deg, N, row_ptr, cursor);
  scatter_kernel<<<(tot+255)/256, 256, 0, stream>>>(esrc, edst, E, N, cursor, csr_src);

  const int gA = (N + NPB - 1)/NPB;   // 500 blocks
  const int gF = (N + 7)/8;           // 1250 blocks (final agg)

  // layer 0 linear
  linear0_kernel<<<gA, 512, 0, stream>>>(x, Ws, a_src, a_dst, N, h0, es0, ed0);

  const float *hc = h0, *esc = es0, *edc = ed0;
  float *hn = h1, *esn = es1, *edn = ed1;

  // fused aggregate(l) + linear(l+1), l = 0..L-2
  for (int l = 0; l < L-1; l++){
    fused_kernel<4><<<gA, 512, 0, stream>>>(hc, esc, edc, row_ptr, csr_src,
                                            bs + (size_t)l*D,
                                            Ws + (size_t)(l+1)*D*D, a_src + (size_t)(l+1)*D, a_dst + (size_t)(l+1)*D,
                                            N, hn, esn, edn);
    const float* tf;
    tf = hc;  hc = hn;  hn = (float*)tf;
    tf = esc; esc = esn; esn = (float*)tf;
    tf = edc; edc = edn; edn = (float*)tf;
  }

  // fused aggregate(L-1) + last linear (heads=1)
  fused_kernel<1><<<gA, 512, 0, stream>>>(hc, esc, edc, row_ptr, csr_src,
                                          bs + (size_t)(L-1)*D,
                                          W_last, a_src_last, a_dst_last,
                                          N, hn, esn, edn);
  {
    const float* tf;
    tf = hc;  hc = hn;  hn = (float*)tf;
    tf = esc; esc = esn; esn = (float*)tf;
    tf = edc; edc = edn; edn = (float*)tf;
  }

  // final aggregation (heads=1, no relu) -> d_out
  final_agg_kernel<<<gF, 512, 0, stream>>>(hc, esc, edc, row_ptr, csr_src, b_last, (float*)d_out, N);
}